// Round 4
// baseline (433.899 us; speedup 1.0000x reference)
//
#include <hip/hip_runtime.h>

// AP (average precision @ IoU 0.5/0.75) for B=256, N=4000, G=50.
// Strategy: greedy TP matching per (batch,thr) -> <=12800 TP elements per thr;
// exact stable-descending-sort ranks of TPs via 65536-bucket counting sort of
// the 1.024M confidences; AP from TP ranks only (suffix-max of precision is
// attained at TP positions). No full argsort needed.
//
// R1: pos_kernel 390us (latency-bound global loop) -> LDS+int4 broadcast.
// R2: tp_kernel rewrite (ballot cand masks + bitmask greedy): 161->150us only.
// R3 post-mortem: 32MB WRITE_SIZE on tp is the 1M hist atomics' TCC write
//     accounting, NOT spills. Real cost: IoU computed twice (per-thr blocks),
//     only 8 waves/CU, and a 7-deep ds_bpermute argmin x50 tail.
// R4: one 1024-thread block per batch; each IoU feeds BOTH thresholds'
//     ballots; greedy argmin via ballot+ffsll (no shuffles); waves 0/1 run
//     the two thresholds' greedy in parallel. scatter writes interleaved
//     (conf,idx) pairs; scan vectorized uint4.

#define B_ 256
#define N_ 4000
#define G_ 50
#define M_ (B_ * N_)        // 1,024,000 proposals total
#define NL_ (B_ * G_)       // 12,800 labels total (= n_labels)
#define NBKT 65536

__device__ __forceinline__ unsigned bucket_of(float c) {
    unsigned b = (unsigned)(c * 65536.0f);
    return b > 65535u ? 65535u : b;
}

// ---- Phase 1: greedy matching for BOTH thresholds + histogram. ------------
// One 1024-thread block per batch.
__global__ __launch_bounds__(1024) void tp_kernel(
    const float* __restrict__ seg,   // [B,N,2]
    const float* __restrict__ gts,   // [B,G,2]
    const float* __restrict__ conf,  // [B,N]
    int* __restrict__ tpCount,       // [2], pre-zeroed
    int* __restrict__ tpIdx,         // [2][NL_]
    unsigned* __restrict__ hist)     // [NBKT], pre-zeroed
{
    const int tid  = threadIdx.x;
    const int lane = tid & 63;
    const int wv   = tid >> 6;            // wave id 0..15
    const int b    = blockIdx.x;

    __shared__ float2 gtl[G_];                           // 400 B
    __shared__ unsigned long long cand[2][G_][64];       // 51.2 KiB

    if (tid < G_) gtl[tid] = ((const float2*)gts)[b * G_ + tid];

    // histogram: each block covers its batch's 4000 scores exactly once
    const float* cb = conf + (size_t)b * N_;
    #pragma unroll
    for (int s = 0; s < 4; ++s) {
        int n = s * 1024 + tid;
        if (n < N_) atomicAdd(&hist[bucket_of(cb[n])], 1u);
    }
    __syncthreads();

    // Phase A: one IoU per (proposal, gt), ballot into both thresholds' masks.
    const float2* sb = (const float2*)(seg + (size_t)b * (N_ * 2));
    #pragma unroll
    for (int s = 0; s < 4; ++s) {
        int n = s * 1024 + tid;
        float pmin, pmax;
        if (n < N_) { float2 v = sb[n]; pmin = v.x; pmax = v.y; }
        else { pmin = 1e9f; pmax = 1e9f; }   // sentinel -> iou 0
        const int q = s * 16 + wv;           // qword covering this wave's 64 props
        float plen = pmax - pmin;
        for (int g = 0; g < G_; ++g) {
            float2 gt = gtl[g];              // LDS broadcast
            float inter = fmaxf(fminf(pmax, gt.y) - fmaxf(pmin, gt.x), 0.0f);
            float uni = plen + (gt.y - gt.x) - inter;   // same op order as ref
            float iou = inter / uni;
            unsigned long long m0 = __ballot(iou > 0.5f);
            unsigned long long m1 = __ballot(iou > 0.75f);
            if (lane == 0) { cand[0][g][q] = m0; cand[1][g][q] = m1; }
        }
    }
    __syncthreads();

    // Phase B: wave 0 -> thr 0.5, wave 1 -> thr 0.75. Greedy via ballot+ffs.
    if (wv < 2) {
        const int thr_i = wv;
        unsigned long long used = 0ull;      // proposals [lane*64, lane*64+64)
        for (int g = 0; g < G_; ++g) {
            unsigned long long c = cand[thr_i][g][lane] & ~used;
            unsigned long long ball = __ballot(c != 0ull);
            if (ball) {
                int fl = __ffsll(ball) - 1;  // lowest lane = lowest proposal range
                if (lane == fl) used |= (c & (0ull - c));   // lowest set bit
            }
        }
        int cpop = __popcll(used);
        if (cpop) {
            int pos = atomicAdd(&tpCount[thr_i], cpop);
            unsigned long long u = used;
            while (u) {
                int bit = __ffsll(u) - 1;
                u &= u - 1;
                tpIdx[thr_i * NL_ + pos++] = b * N_ + lane * 64 + bit;
            }
        }
    }
}

// ---- Phase 2b: exclusive scan of 65536 bins, single block -----------------
__global__ __launch_bounds__(1024) void scan_kernel(
    const unsigned* __restrict__ hist, unsigned* __restrict__ start,
    unsigned* __restrict__ cursor)
{
    __shared__ unsigned part[1024];
    int t = threadIdx.x;
    unsigned loc[64];
    unsigned s = 0;
    const uint4* h4 = (const uint4*)(hist + t * 64);
    #pragma unroll
    for (int k = 0; k < 16; ++k) {
        uint4 v = h4[k];
        loc[4 * k + 0] = s; s += v.x;
        loc[4 * k + 1] = s; s += v.y;
        loc[4 * k + 2] = s; s += v.z;
        loc[4 * k + 3] = s; s += v.w;
    }
    part[t] = s;
    __syncthreads();
    for (int off = 1; off < 1024; off <<= 1) {   // inclusive Hillis-Steele
        unsigned add = (t >= off) ? part[t - off] : 0u;
        unsigned v = part[t];
        __syncthreads();
        part[t] = v + add;
        __syncthreads();
    }
    unsigned base = (t == 0) ? 0u : part[t - 1];
    uint4* st4 = (uint4*)(start + t * 64);
    uint4* cu4 = (uint4*)(cursor + t * 64);
    #pragma unroll
    for (int k = 0; k < 16; ++k) {
        uint4 v = make_uint4(base + loc[4 * k], base + loc[4 * k + 1],
                             base + loc[4 * k + 2], base + loc[4 * k + 3]);
        st4[k] = v;
        cu4[k] = v;
    }
}

// ---- Phase 2c: scatter into bucket-grouped order (interleaved pairs) ------
__global__ void scatter_kernel(const float* __restrict__ conf,
                               unsigned* __restrict__ cursor,
                               float2* __restrict__ sPair)
{
    int i = blockIdx.x * blockDim.x + threadIdx.x;
    if (i < M_) {
        float c = conf[i];
        unsigned b = bucket_of(c);
        unsigned pos = atomicAdd(&cursor[b], 1u);
        sPair[pos] = make_float2(c, __uint_as_float((unsigned)i));
    }
}

// ---- Phase 2d: exact rank of each TP (stable descending order) ------------
__global__ void rank_kernel(const float* __restrict__ conf,
                            const int* __restrict__ tpCount,
                            const int* __restrict__ tpIdx,
                            const unsigned* __restrict__ hist,
                            const unsigned* __restrict__ start,
                            const float2* __restrict__ sPair,
                            int* __restrict__ tpRank)
{
    int thr_i = blockIdx.y;
    int t = blockIdx.x * blockDim.x + threadIdx.x;
    if (t >= tpCount[thr_i]) return;
    int e = tpIdx[thr_i * NL_ + t];
    float c = conf[e];
    unsigned b = bucket_of(c);
    unsigned lo = start[b], n = hist[b];
    int cnt = M_ - (int)lo - (int)n;   // everything in strictly-better buckets
    for (unsigned j = lo; j < lo + n; ++j) {
        float2 p = sPair[j];
        unsigned si = __float_as_uint(p.y);
        cnt += (p.x > c) || (p.x == c && si < (unsigned)e);
    }
    tpRank[thr_i * NL_ + t] = cnt;
}

// ---- Phase 3a: position of each TP among TPs, via LDS ---------------------
__global__ __launch_bounds__(256) void pos_kernel(
    const int* __restrict__ tpCount,
    const int* __restrict__ tpRank,
    int* __restrict__ sortedRank)
{
    __shared__ alignas(16) int lr[NL_];
    const int thr_i = blockIdx.y;
    const int T = tpCount[thr_i];
    const int* base = tpRank + thr_i * NL_;
    for (int i = threadIdx.x; i < NL_; i += 256)
        lr[i] = (i < T) ? base[i] : 0x7FFFFFFF;   // sentinel never counts as < r
    __syncthreads();

    int t = blockIdx.x * 256 + threadIdx.x;
    if (t >= T) return;
    int r = lr[t];
    int p = 0;
    const int4* l4 = (const int4*)lr;
    #pragma unroll 8
    for (int u = 0; u < NL_ / 4; ++u) {   // wave-uniform addr -> LDS broadcast
        int4 v = l4[u];
        p += (v.x < r) + (v.y < r) + (v.z < r) + (v.w < r);
    }
    sortedRank[thr_i * NL_ + p] = r;
}

// ---- Phase 3b: AP from sorted TP ranks. One block per threshold. ----------
__global__ __launch_bounds__(1024) void ap_kernel(const int* __restrict__ tpCount,
                                                  const int* __restrict__ sortedRank,
                                                  float* __restrict__ out)
{
    const int C = 13;   // 1024*13 = 13312 >= NL_
    int thr_i = blockIdx.x;
    int T = tpCount[thr_i];
    int t = threadIdx.x;
    const int* sr = sortedRank + thr_i * NL_;

    float pr[C]; int rk[C];
    #pragma unroll
    for (int k = 0; k < C; ++k) {
        int i = t * C + k;
        if (i < T) { rk[k] = sr[i]; pr[k] = (float)(i + 1) / (float)(rk[k] + 1); }
        else { rk[k] = -1; pr[k] = -1.0f; }
    }
    float suf[C];
    float run = -1.0f;
    #pragma unroll
    for (int k = C - 1; k >= 0; --k) { run = fmaxf(run, pr[k]); suf[k] = run; }

    __shared__ float cmax[1024];
    cmax[t] = run;
    __syncthreads();
    for (int off = 1; off < 1024; off <<= 1) {   // inclusive suffix-max scan
        float v = cmax[t];
        float o = (t + off < 1024) ? cmax[t + off] : -1.0f;
        __syncthreads();
        cmax[t] = fmaxf(v, o);
        __syncthreads();
    }
    float follow = (t + 1 < 1024) ? cmax[t + 1] : -1.0f;

    double acc = 0.0;
    #pragma unroll
    for (int k = 0; k < C; ++k) {
        int i = t * C + k;
        if (i < T && rk[k] >= 1) {    // sorted position 0 excluded by the ref curve
            float smax = fmaxf(suf[k], follow);
            float rhi = (float)(i + 1) / 12800.0f;
            float rlo = (float)i / 12800.0f;
            acc += (double)((rhi - rlo) * smax);
        }
    }
    __shared__ double red[1024];
    red[t] = acc;
    __syncthreads();
    for (int off = 512; off >= 1; off >>= 1) {
        if (t < off) red[t] += red[t + off];
        __syncthreads();
    }
    if (t == 0) out[thr_i] = (float)red[0];
}

extern "C" void kernel_launch(void* const* d_in, const int* in_sizes, int n_in,
                              void* d_out, int out_size, void* d_ws, size_t ws_size,
                              hipStream_t stream) {
    const float* scores = (const float*)d_in[0];   // [B,N]
    const float* seg    = (const float*)d_in[1];   // [B,N,2]
    const float* gts    = (const float*)d_in[2];   // [B,G,2]
    float* out = (float*)d_out;

    char* ws = (char*)d_ws;
    int*      tpCount    = (int*)ws;                                    // 8 B (+pad)
    unsigned* hist       = (unsigned*)(ws + 256);                       // 256 KiB
    unsigned* start      = (unsigned*)(ws + 256 + 262144);              // 256 KiB
    unsigned* cursor     = (unsigned*)(ws + 256 + 2 * 262144);          // 256 KiB
    int*      tpIdx      = (int*)(ws + 256 + 3 * 262144);               // 100 KiB
    int*      tpRank     = tpIdx + 2 * NL_;                             // 100 KiB
    int*      sortedRank = tpRank + 2 * NL_;                            // 100 KiB
    float2*   sPair      = (float2*)(ws + 256 + 3 * 262144 + 3 * 102400);// 8 MB
    (void)ws_size; (void)in_sizes; (void)n_in; (void)out_size;

    // zero tpCount + hist (ws is poisoned 0xAA before every call)
    hipMemsetAsync(ws, 0, 256 + NBKT * 4, stream);

    tp_kernel<<<B_, 1024, 0, stream>>>(seg, gts, scores, tpCount, tpIdx, hist);
    scan_kernel<<<1, 1024, 0, stream>>>(hist, start, cursor);
    scatter_kernel<<<M_ / 256, 256, 0, stream>>>(scores, cursor, sPair);
    rank_kernel<<<dim3(NL_ / 256, 2), 256, 0, stream>>>(scores, tpCount, tpIdx,
                                                        hist, start, sPair, tpRank);
    pos_kernel<<<dim3(NL_ / 256, 2), 256, 0, stream>>>(tpCount, tpRank, sortedRank);
    ap_kernel<<<2, 1024, 0, stream>>>(tpCount, sortedRank, out);
}

// Round 6
// 422.669 us; speedup vs baseline: 1.0266x; 1.0266x over previous
//
#include <hip/hip_runtime.h>

// AP (average precision @ IoU 0.5/0.75) for B=256, N=4000, G=50.
// Strategy: greedy TP matching -> <=50 TPs per (batch,thr); exact stable
// descending-sort ranks of TPs via 1024-bucket counting sort of the 1.024M
// confidences; AP from TP ranks only.
//
// R1: pos_kernel 390us (latency-bound global loop) -> LDS+int4 broadcast.
// R2-R4: tp_kernel stuck ~145us: WRITE_SIZE == 32MB == 1M x 32B device-scope
//     hist atomics; device atomics resolve at memory side (~8.4G/s ceiling).
// R5: zero-global-atomic redesign CRASHED: tp LDS 84KB > 64KB workgroup limit
//     (launch fail -> poisoned pbh -> scatter OOB) + 20.4MB ws footprint.
// R6: same design, resized: NBKT=1024 (tp LDS 55.7KB, scatter LDS 8KB),
//     s1 converts pbh to prefix IN PLACE (no tmp buffer). ws = 9.04MB,
//     under the 9.29MB known-good envelope. Zero global atomics, no memset.

#define B_ 256
#define N_ 4000
#define G_ 50
#define M_ (B_ * N_)        // 1,024,000 proposals total
#define NL_ (B_ * G_)       // 12,800 labels total (= n_labels)
#define NBKT 1024

__device__ __forceinline__ unsigned bucket_of(float c) {
    unsigned b = (unsigned)(c * 1024.0f);
    return b > (NBKT - 1) ? (NBKT - 1) : b;
}

// ---- Phase 1: greedy matching (both thr) + LDS-private histogram. ---------
// One 1024-thread block per batch. No global atomics.
__global__ __launch_bounds__(1024) void tp_kernel(
    const float* __restrict__ seg,    // [B,N,2]
    const float* __restrict__ gts,    // [B,G,2]
    const float* __restrict__ conf,   // [B,N]
    int* __restrict__ tpIdx,          // [2][NL_], slots [b*50, b*50+cnt)
    int* __restrict__ cnt,            // [2][B_]
    unsigned short* __restrict__ pbh) // [B_][NBKT] per-batch histogram
{
    const int tid  = threadIdx.x;
    const int lane = tid & 63;
    const int wv   = tid >> 6;            // wave id 0..15
    const int b    = blockIdx.x;

    __shared__ float2 gtl[G_];                           // 400 B
    __shared__ unsigned long long cand[2][G_][64];       // 51.2 KiB
    __shared__ unsigned hls[NBKT];                       // 4 KiB
    __shared__ int lcnt[2];                              // total 55.7 KiB < 64 KiB

    if (tid < NBKT) hls[tid] = 0u;
    if (tid < G_) gtl[tid] = ((const float2*)gts)[b * G_ + tid];
    if (tid < 2) lcnt[tid] = 0;
    __syncthreads();

    // LDS-private histogram of this batch's 4000 scores
    const float* cb = conf + (size_t)b * N_;
    #pragma unroll
    for (int s = 0; s < 4; ++s) {
        int n = s * 1024 + tid;
        if (n < N_) atomicAdd(&hls[bucket_of(cb[n])], 1u);
    }

    // Phase A: one IoU per (proposal, gt), ballot into both thresholds' masks.
    const float2* sb = (const float2*)(seg + (size_t)b * (N_ * 2));
    #pragma unroll
    for (int s = 0; s < 4; ++s) {
        int n = s * 1024 + tid;
        float pmin, pmax;
        if (n < N_) { float2 v = sb[n]; pmin = v.x; pmax = v.y; }
        else { pmin = 1e9f; pmax = 1e9f; }   // sentinel -> iou 0
        const int q = s * 16 + wv;           // qword covering this wave's 64 props
        float plen = pmax - pmin;
        for (int g = 0; g < G_; ++g) {
            float2 gt = gtl[g];              // LDS broadcast
            float inter = fmaxf(fminf(pmax, gt.y) - fmaxf(pmin, gt.x), 0.0f);
            float uni = plen + (gt.y - gt.x) - inter;   // same op order as ref
            float iou = inter / uni;
            unsigned long long m0 = __ballot(iou > 0.5f);
            unsigned long long m1 = __ballot(iou > 0.75f);
            if (lane == 0) { cand[0][g][q] = m0; cand[1][g][q] = m1; }
        }
    }
    __syncthreads();   // cand complete + hist complete

    // write per-batch histogram row (u16; per-batch bin count <= 4000)
    if (tid < NBKT) pbh[(size_t)b * NBKT + tid] = (unsigned short)hls[tid];

    // Phase B: wave 0 -> thr 0.5, wave 1 -> thr 0.75. Greedy via ballot+ffs.
    if (wv < 2) {
        const int thr_i = wv;
        unsigned long long used = 0ull;      // proposals [lane*64, lane*64+64)
        for (int g = 0; g < G_; ++g) {
            unsigned long long c = cand[thr_i][g][lane] & ~used;
            unsigned long long ball = __ballot(c != 0ull);
            if (ball) {
                int fl = __ffsll(ball) - 1;  // lowest lane = lowest proposal range
                if (lane == fl) used |= (c & (0ull - c));   // lowest set bit
            }
        }
        int cpop = __popcll(used);
        if (cpop) {
            int j = atomicAdd(&lcnt[thr_i], cpop);   // LDS atomic, block-local
            unsigned long long u = used;
            while (u) {
                int bit = __ffsll(u) - 1;
                u &= u - 1;
                tpIdx[thr_i * NL_ + b * G_ + j++] = b * N_ + lane * 64 + bit;
            }
        }
    }
    __syncthreads();
    if (tid < 2) cnt[tid * B_ + b] = lcnt[tid];
}

// ---- S1: in-place per-(batch,bin) exclusive prefix over batches + totals --
__global__ __launch_bounds__(256) void s1_kernel(
    unsigned short* __restrict__ pbh,        // [B_][NBKT] -> becomes prefix
    unsigned* __restrict__ total)            // [NBKT]
{
    int bin = blockIdx.x * 256 + threadIdx.x;
    unsigned run = 0;
    for (int b = 0; b < B_; ++b) {           // coalesced across threads
        size_t o = (size_t)b * NBKT + bin;
        unsigned v = pbh[o];
        pbh[o] = (unsigned short)run;
        run += v;
    }
    total[bin] = run;
}

// ---- S2: exclusive scan of 1024 bin totals, single block ------------------
__global__ __launch_bounds__(1024) void s2_kernel(
    const unsigned* __restrict__ total, unsigned* __restrict__ binStart)
{
    __shared__ unsigned part[1024];
    int t = threadIdx.x;
    part[t] = total[t];
    __syncthreads();
    for (int off = 1; off < 1024; off <<= 1) {   // inclusive Hillis-Steele
        unsigned add = (t >= off) ? part[t - off] : 0u;
        unsigned v = part[t];
        __syncthreads();
        part[t] = v + add;
        __syncthreads();
    }
    binStart[t] = (t == 0) ? 0u : part[t - 1];
}

// ---- Scatter: deterministic positions, zero global atomics ----------------
// One block per batch: pos = binStart[bin] + prefix[b][bin] + LDS-local offset.
__global__ __launch_bounds__(1024) void scatter_kernel(
    const float* __restrict__ conf,
    const unsigned short* __restrict__ pbh,  // now the exclusive prefix
    const unsigned* __restrict__ binStart,
    float2* __restrict__ sPair)
{
    __shared__ unsigned baseB[NBKT];   // 4 KiB
    __shared__ unsigned lofs[NBKT];    // 4 KiB
    const int tid = threadIdx.x;
    const int b = blockIdx.x;
    if (tid < NBKT) {
        baseB[tid] = binStart[tid] + pbh[(size_t)b * NBKT + tid];
        lofs[tid] = 0u;
    }
    __syncthreads();
    const float* cb = conf + (size_t)b * N_;
    #pragma unroll
    for (int s = 0; s < 4; ++s) {
        int n = s * 1024 + tid;
        if (n < N_) {
            float c = cb[n];
            unsigned bin = bucket_of(c);
            unsigned lo = atomicAdd(&lofs[bin], 1u);   // LDS atomic
            sPair[baseB[bin] + lo] = make_float2(c, __uint_as_float((unsigned)(b * N_ + n)));
        }
    }
}

// ---- Rank: exact stable-descending rank of each TP slot -------------------
__global__ __launch_bounds__(256) void rank_kernel(
    const float* __restrict__ conf,
    const int* __restrict__ tpIdx,
    const int* __restrict__ cnt,
    const unsigned* __restrict__ total,
    const unsigned* __restrict__ binStart,
    const float2* __restrict__ sPair,
    int* __restrict__ tpRank)
{
    int thr_i = blockIdx.y;
    int t = blockIdx.x * 256 + threadIdx.x;
    int batch = t / G_;
    int j = t - batch * G_;
    if (j < cnt[thr_i * B_ + batch]) {
        int e = tpIdx[thr_i * NL_ + t];
        float c = conf[e];
        unsigned bin = bucket_of(c);
        unsigned lo = binStart[bin], n = total[bin];
        int r = M_ - (int)lo - (int)n;   // strictly-better buckets
        for (unsigned k = lo; k < lo + n; ++k) {
            float2 p = sPair[k];
            unsigned si = __float_as_uint(p.y);
            r += (p.x > c) || (p.x == c && si < (unsigned)e);
        }
        tpRank[thr_i * NL_ + t] = r;
    } else {
        tpRank[thr_i * NL_ + t] = M_ + t;   // distinct sentinel, > any real rank
    }
}

// ---- Pos: full 12800-permutation via LDS broadcast counting ---------------
__global__ __launch_bounds__(256) void pos_kernel(
    const int* __restrict__ tpRank,
    int* __restrict__ sortedRank)
{
    __shared__ alignas(16) int lr[NL_];
    const int thr_i = blockIdx.y;
    const int* base = tpRank + thr_i * NL_;
    for (int i = threadIdx.x; i < NL_; i += 256) lr[i] = base[i];
    __syncthreads();

    int t = blockIdx.x * 256 + threadIdx.x;
    int r = lr[t];
    int p = 0;
    const int4* l4 = (const int4*)lr;
    #pragma unroll 8
    for (int u = 0; u < NL_ / 4; ++u) {   // wave-uniform addr -> LDS broadcast
        int4 v = l4[u];
        p += (v.x < r) + (v.y < r) + (v.z < r) + (v.w < r);
    }
    sortedRank[thr_i * NL_ + p] = r;      // bijection: every slot written
}

// ---- AP from sorted TP ranks. One block per threshold. --------------------
__global__ __launch_bounds__(1024) void ap_kernel(const int* __restrict__ sortedRank,
                                                  float* __restrict__ out)
{
    const int C = 13;   // 1024*13 = 13312 >= NL_
    int thr_i = blockIdx.x;
    int t = threadIdx.x;
    const int* sr = sortedRank + thr_i * NL_;

    float pr[C]; int rk[C];
    #pragma unroll
    for (int k = 0; k < C; ++k) {
        int i = t * C + k;
        rk[k] = (i < NL_) ? sr[i] : 0x7FFFFFFF;
        pr[k] = (rk[k] < M_) ? (float)(i + 1) / (float)(rk[k] + 1) : -1.0f;
    }
    float suf[C];
    float run = -1.0f;
    #pragma unroll
    for (int k = C - 1; k >= 0; --k) { run = fmaxf(run, pr[k]); suf[k] = run; }

    __shared__ float cmax[1024];
    cmax[t] = run;
    __syncthreads();
    for (int off = 1; off < 1024; off <<= 1) {   // inclusive suffix-max scan
        float v = cmax[t];
        float o = (t + off < 1024) ? cmax[t + off] : -1.0f;
        __syncthreads();
        cmax[t] = fmaxf(v, o);
        __syncthreads();
    }
    float follow = (t + 1 < 1024) ? cmax[t + 1] : -1.0f;

    double acc = 0.0;
    #pragma unroll
    for (int k = 0; k < C; ++k) {
        int i = t * C + k;
        if (rk[k] >= 1 && rk[k] < M_) {   // global rank 0 excluded by ref curve
            float smax = fmaxf(suf[k], follow);
            float rhi = (float)(i + 1) / 12800.0f;
            float rlo = (float)i / 12800.0f;
            acc += (double)((rhi - rlo) * smax);
        }
    }
    __shared__ double red[1024];
    red[t] = acc;
    __syncthreads();
    for (int off = 512; off >= 1; off >>= 1) {
        if (t < off) red[t] += red[t + off];
        __syncthreads();
    }
    if (t == 0) out[thr_i] = (float)red[0];
}

extern "C" void kernel_launch(void* const* d_in, const int* in_sizes, int n_in,
                              void* d_out, int out_size, void* d_ws, size_t ws_size,
                              hipStream_t stream) {
    const float* scores = (const float*)d_in[0];   // [B,N]
    const float* seg    = (const float*)d_in[1];   // [B,N,2]
    const float* gts    = (const float*)d_in[2];   // [B,G,2]
    float* out = (float*)d_out;

    char* p = (char*)d_ws;
    int*            cnt        = (int*)p;             p += 4096;                  // 2KB used
    int*            tpIdx      = (int*)p;             p += 2 * NL_ * 4;           // 100 KB
    int*            tpRank     = (int*)p;             p += 2 * NL_ * 4;           // 100 KB
    int*            sortedRank = (int*)p;             p += 2 * NL_ * 4;           // 100 KB
    unsigned*       total      = (unsigned*)p;        p += NBKT * 4;              // 4 KB
    unsigned*       binStart   = (unsigned*)p;        p += NBKT * 4;              // 4 KB
    unsigned short* pbh        = (unsigned short*)p;  p += (size_t)B_ * NBKT * 2; // 512 KB
    float2*         sPair      = (float2*)p;          p += (size_t)M_ * 8;        // 8 MB
    (void)ws_size; (void)in_sizes; (void)n_in; (void)out_size;     // total ~9.04 MB

    // No memset: every workspace word read downstream is written upstream.
    tp_kernel<<<B_, 1024, 0, stream>>>(seg, gts, scores, tpIdx, cnt, pbh);
    s1_kernel<<<NBKT / 256, 256, 0, stream>>>(pbh, total);
    s2_kernel<<<1, 1024, 0, stream>>>(total, binStart);
    scatter_kernel<<<B_, 1024, 0, stream>>>(scores, pbh, binStart, sPair);
    rank_kernel<<<dim3(NL_ / 256, 2), 256, 0, stream>>>(scores, tpIdx, cnt,
                                                        total, binStart, sPair, tpRank);
    pos_kernel<<<dim3(NL_ / 256, 2), 256, 0, stream>>>(tpRank, sortedRank);
    ap_kernel<<<2, 1024, 0, stream>>>(sortedRank, out);
}

// Round 7
// 259.551 us; speedup vs baseline: 1.6717x; 1.6285x over previous
//
#include <hip/hip_runtime.h>

// AP (average precision @ IoU 0.5/0.75) for B=256, N=4000, G=50.
// Strategy: greedy TP matching -> <=50 TPs per (batch,thr); exact stable
// descending-sort ranks of TPs via 1024-bucket counting sort of the 1.024M
// confidences; AP from TP ranks only.
//
// R1: pos_kernel 390us (latency-bound global loop) -> LDS+int4 broadcast.
// R2-R4: tp_kernel stuck ~145us: WRITE_SIZE == 32MB == 1M x 32B device-scope
//     hist atomics; device atomics resolve at memory side (~8.4G/s ceiling).
// R5: zero-global-atomic redesign CRASHED (tp LDS 84KB > 64KB; ws 20MB).
// R6: resized (NBKT=1024, in-place prefix): passed, 423us. New top:
//     rank_kernel 195us -- ONE thread serially scanning its ~1000-elem
//     bucket (latency-bound, occupancy 4%).
// R7: rank is one WAVE per TP slot: lanes stride the bucket (coalesced
//     float2), per-iter count via __popcll(__ballot(pred)) -> wave-uniform
//     sum, no reduction tail. 6400 blocks in flight.

#define B_ 256
#define N_ 4000
#define G_ 50
#define M_ (B_ * N_)        // 1,024,000 proposals total
#define NL_ (B_ * G_)       // 12,800 labels total (= n_labels)
#define NBKT 1024

__device__ __forceinline__ unsigned bucket_of(float c) {
    unsigned b = (unsigned)(c * 1024.0f);
    return b > (NBKT - 1) ? (NBKT - 1) : b;
}

// ---- Phase 1: greedy matching (both thr) + LDS-private histogram. ---------
// One 1024-thread block per batch. No global atomics.
__global__ __launch_bounds__(1024) void tp_kernel(
    const float* __restrict__ seg,    // [B,N,2]
    const float* __restrict__ gts,    // [B,G,2]
    const float* __restrict__ conf,   // [B,N]
    int* __restrict__ tpIdx,          // [2][NL_], slots [b*50, b*50+cnt)
    int* __restrict__ cnt,            // [2][B_]
    unsigned short* __restrict__ pbh) // [B_][NBKT] per-batch histogram
{
    const int tid  = threadIdx.x;
    const int lane = tid & 63;
    const int wv   = tid >> 6;            // wave id 0..15
    const int b    = blockIdx.x;

    __shared__ float2 gtl[G_];                           // 400 B
    __shared__ unsigned long long cand[2][G_][64];       // 51.2 KiB
    __shared__ unsigned hls[NBKT];                       // 4 KiB
    __shared__ int lcnt[2];                              // total 55.7 KiB < 64 KiB

    if (tid < NBKT) hls[tid] = 0u;
    if (tid < G_) gtl[tid] = ((const float2*)gts)[b * G_ + tid];
    if (tid < 2) lcnt[tid] = 0;
    __syncthreads();

    // LDS-private histogram of this batch's 4000 scores
    const float* cb = conf + (size_t)b * N_;
    #pragma unroll
    for (int s = 0; s < 4; ++s) {
        int n = s * 1024 + tid;
        if (n < N_) atomicAdd(&hls[bucket_of(cb[n])], 1u);
    }

    // Phase A: one IoU per (proposal, gt), ballot into both thresholds' masks.
    const float2* sb = (const float2*)(seg + (size_t)b * (N_ * 2));
    #pragma unroll
    for (int s = 0; s < 4; ++s) {
        int n = s * 1024 + tid;
        float pmin, pmax;
        if (n < N_) { float2 v = sb[n]; pmin = v.x; pmax = v.y; }
        else { pmin = 1e9f; pmax = 1e9f; }   // sentinel -> iou 0
        const int q = s * 16 + wv;           // qword covering this wave's 64 props
        float plen = pmax - pmin;
        for (int g = 0; g < G_; ++g) {
            float2 gt = gtl[g];              // LDS broadcast
            float inter = fmaxf(fminf(pmax, gt.y) - fmaxf(pmin, gt.x), 0.0f);
            float uni = plen + (gt.y - gt.x) - inter;   // same op order as ref
            float iou = inter / uni;
            unsigned long long m0 = __ballot(iou > 0.5f);
            unsigned long long m1 = __ballot(iou > 0.75f);
            if (lane == 0) { cand[0][g][q] = m0; cand[1][g][q] = m1; }
        }
    }
    __syncthreads();   // cand complete + hist complete

    // write per-batch histogram row (u16; per-batch bin count <= 4000)
    if (tid < NBKT) pbh[(size_t)b * NBKT + tid] = (unsigned short)hls[tid];

    // Phase B: wave 0 -> thr 0.5, wave 1 -> thr 0.75. Greedy via ballot+ffs.
    if (wv < 2) {
        const int thr_i = wv;
        unsigned long long used = 0ull;      // proposals [lane*64, lane*64+64)
        for (int g = 0; g < G_; ++g) {
            unsigned long long c = cand[thr_i][g][lane] & ~used;
            unsigned long long ball = __ballot(c != 0ull);
            if (ball) {
                int fl = __ffsll(ball) - 1;  // lowest lane = lowest proposal range
                if (lane == fl) used |= (c & (0ull - c));   // lowest set bit
            }
        }
        int cpop = __popcll(used);
        if (cpop) {
            int j = atomicAdd(&lcnt[thr_i], cpop);   // LDS atomic, block-local
            unsigned long long u = used;
            while (u) {
                int bit = __ffsll(u) - 1;
                u &= u - 1;
                tpIdx[thr_i * NL_ + b * G_ + j++] = b * N_ + lane * 64 + bit;
            }
        }
    }
    __syncthreads();
    if (tid < 2) cnt[tid * B_ + b] = lcnt[tid];
}

// ---- S1: in-place per-(batch,bin) exclusive prefix over batches + totals --
__global__ __launch_bounds__(256) void s1_kernel(
    unsigned short* __restrict__ pbh,        // [B_][NBKT] -> becomes prefix
    unsigned* __restrict__ total)            // [NBKT]
{
    int bin = blockIdx.x * 256 + threadIdx.x;
    unsigned run = 0;
    for (int b = 0; b < B_; ++b) {           // coalesced across threads
        size_t o = (size_t)b * NBKT + bin;
        unsigned v = pbh[o];
        pbh[o] = (unsigned short)run;
        run += v;
    }
    total[bin] = run;
}

// ---- S2: exclusive scan of 1024 bin totals, single block ------------------
__global__ __launch_bounds__(1024) void s2_kernel(
    const unsigned* __restrict__ total, unsigned* __restrict__ binStart)
{
    __shared__ unsigned part[1024];
    int t = threadIdx.x;
    part[t] = total[t];
    __syncthreads();
    for (int off = 1; off < 1024; off <<= 1) {   // inclusive Hillis-Steele
        unsigned add = (t >= off) ? part[t - off] : 0u;
        unsigned v = part[t];
        __syncthreads();
        part[t] = v + add;
        __syncthreads();
    }
    binStart[t] = (t == 0) ? 0u : part[t - 1];
}

// ---- Scatter: deterministic positions, zero global atomics ----------------
__global__ __launch_bounds__(1024) void scatter_kernel(
    const float* __restrict__ conf,
    const unsigned short* __restrict__ pbh,  // now the exclusive prefix
    const unsigned* __restrict__ binStart,
    float2* __restrict__ sPair)
{
    __shared__ unsigned baseB[NBKT];   // 4 KiB
    __shared__ unsigned lofs[NBKT];    // 4 KiB
    const int tid = threadIdx.x;
    const int b = blockIdx.x;
    if (tid < NBKT) {
        baseB[tid] = binStart[tid] + pbh[(size_t)b * NBKT + tid];
        lofs[tid] = 0u;
    }
    __syncthreads();
    const float* cb = conf + (size_t)b * N_;
    #pragma unroll
    for (int s = 0; s < 4; ++s) {
        int n = s * 1024 + tid;
        if (n < N_) {
            float c = cb[n];
            unsigned bin = bucket_of(c);
            unsigned lo = atomicAdd(&lofs[bin], 1u);   // LDS atomic
            sPair[baseB[bin] + lo] = make_float2(c, __uint_as_float((unsigned)(b * N_ + n)));
        }
    }
}

// ---- Rank: one WAVE per TP slot; lanes stride the bucket ------------------
__global__ __launch_bounds__(256) void rank_kernel(
    const float* __restrict__ conf,
    const int* __restrict__ tpIdx,
    const int* __restrict__ cnt,
    const unsigned* __restrict__ total,
    const unsigned* __restrict__ binStart,
    const float2* __restrict__ sPair,
    int* __restrict__ tpRank)
{
    const int lane = threadIdx.x & 63;
    const int w = (blockIdx.x << 2) | (threadIdx.x >> 6);   // global wave id
    if (w >= 2 * NL_) return;
    const int thr_i = w / NL_;
    const int t = w - thr_i * NL_;
    const int batch = t / G_;
    const int j = t - batch * G_;

    if (j < cnt[thr_i * B_ + batch]) {
        int e = tpIdx[thr_i * NL_ + t];
        float c = conf[e];
        unsigned bin = bucket_of(c);
        unsigned lo = binStart[bin], n = total[bin];
        int r = M_ - (int)lo - (int)n;   // strictly-better buckets
        for (unsigned base = 0; base < n; base += 64) {
            unsigned k = base + lane;
            bool pred = false;
            if (k < n) {
                float2 p = sPair[lo + k];
                unsigned si = __float_as_uint(p.y);
                pred = (p.x > c) || (p.x == c && si < (unsigned)e);
            }
            r += (int)__popcll(__ballot(pred));   // wave-uniform partial sum
        }
        if (lane == 0) tpRank[thr_i * NL_ + t] = r;
    } else {
        if (lane == 0) tpRank[thr_i * NL_ + t] = M_ + t;   // distinct sentinel
    }
}

// ---- Pos: full 12800-permutation via LDS broadcast counting ---------------
__global__ __launch_bounds__(256) void pos_kernel(
    const int* __restrict__ tpRank,
    int* __restrict__ sortedRank)
{
    __shared__ alignas(16) int lr[NL_];
    const int thr_i = blockIdx.y;
    const int* base = tpRank + thr_i * NL_;
    for (int i = threadIdx.x; i < NL_; i += 256) lr[i] = base[i];
    __syncthreads();

    int t = blockIdx.x * 256 + threadIdx.x;
    int r = lr[t];
    int p = 0;
    const int4* l4 = (const int4*)lr;
    #pragma unroll 8
    for (int u = 0; u < NL_ / 4; ++u) {   // wave-uniform addr -> LDS broadcast
        int4 v = l4[u];
        p += (v.x < r) + (v.y < r) + (v.z < r) + (v.w < r);
    }
    sortedRank[thr_i * NL_ + p] = r;      // bijection: every slot written
}

// ---- AP from sorted TP ranks. One block per threshold. --------------------
__global__ __launch_bounds__(1024) void ap_kernel(const int* __restrict__ sortedRank,
                                                  float* __restrict__ out)
{
    const int C = 13;   // 1024*13 = 13312 >= NL_
    int thr_i = blockIdx.x;
    int t = threadIdx.x;
    const int* sr = sortedRank + thr_i * NL_;

    float pr[C]; int rk[C];
    #pragma unroll
    for (int k = 0; k < C; ++k) {
        int i = t * C + k;
        rk[k] = (i < NL_) ? sr[i] : 0x7FFFFFFF;
        pr[k] = (rk[k] < M_) ? (float)(i + 1) / (float)(rk[k] + 1) : -1.0f;
    }
    float suf[C];
    float run = -1.0f;
    #pragma unroll
    for (int k = C - 1; k >= 0; --k) { run = fmaxf(run, pr[k]); suf[k] = run; }

    __shared__ float cmax[1024];
    cmax[t] = run;
    __syncthreads();
    for (int off = 1; off < 1024; off <<= 1) {   // inclusive suffix-max scan
        float v = cmax[t];
        float o = (t + off < 1024) ? cmax[t + off] : -1.0f;
        __syncthreads();
        cmax[t] = fmaxf(v, o);
        __syncthreads();
    }
    float follow = (t + 1 < 1024) ? cmax[t + 1] : -1.0f;

    double acc = 0.0;
    #pragma unroll
    for (int k = 0; k < C; ++k) {
        int i = t * C + k;
        if (rk[k] >= 1 && rk[k] < M_) {   // global rank 0 excluded by ref curve
            float smax = fmaxf(suf[k], follow);
            float rhi = (float)(i + 1) / 12800.0f;
            float rlo = (float)i / 12800.0f;
            acc += (double)((rhi - rlo) * smax);
        }
    }
    __shared__ double red[1024];
    red[t] = acc;
    __syncthreads();
    for (int off = 512; off >= 1; off >>= 1) {
        if (t < off) red[t] += red[t + off];
        __syncthreads();
    }
    if (t == 0) out[thr_i] = (float)red[0];
}

extern "C" void kernel_launch(void* const* d_in, const int* in_sizes, int n_in,
                              void* d_out, int out_size, void* d_ws, size_t ws_size,
                              hipStream_t stream) {
    const float* scores = (const float*)d_in[0];   // [B,N]
    const float* seg    = (const float*)d_in[1];   // [B,N,2]
    const float* gts    = (const float*)d_in[2];   // [B,G,2]
    float* out = (float*)d_out;

    char* p = (char*)d_ws;
    int*            cnt        = (int*)p;             p += 4096;                  // 2KB used
    int*            tpIdx      = (int*)p;             p += 2 * NL_ * 4;           // 100 KB
    int*            tpRank     = (int*)p;             p += 2 * NL_ * 4;           // 100 KB
    int*            sortedRank = (int*)p;             p += 2 * NL_ * 4;           // 100 KB
    unsigned*       total      = (unsigned*)p;        p += NBKT * 4;              // 4 KB
    unsigned*       binStart   = (unsigned*)p;        p += NBKT * 4;              // 4 KB
    unsigned short* pbh        = (unsigned short*)p;  p += (size_t)B_ * NBKT * 2; // 512 KB
    float2*         sPair      = (float2*)p;          p += (size_t)M_ * 8;        // 8 MB
    (void)ws_size; (void)in_sizes; (void)n_in; (void)out_size;     // total ~9.04 MB

    // No memset: every workspace word read downstream is written upstream.
    tp_kernel<<<B_, 1024, 0, stream>>>(seg, gts, scores, tpIdx, cnt, pbh);
    s1_kernel<<<NBKT / 256, 256, 0, stream>>>(pbh, total);
    s2_kernel<<<1, 1024, 0, stream>>>(total, binStart);
    scatter_kernel<<<B_, 1024, 0, stream>>>(scores, pbh, binStart, sPair);
    rank_kernel<<<(2 * NL_ + 3) / 4, 256, 0, stream>>>(scores, tpIdx, cnt,
                                                       total, binStart, sPair, tpRank);
    pos_kernel<<<dim3(NL_ / 256, 2), 256, 0, stream>>>(tpRank, sortedRank);
    ap_kernel<<<2, 1024, 0, stream>>>(sortedRank, out);
}

// Round 8
// 203.950 us; speedup vs baseline: 2.1275x; 1.2726x over previous
//
#include <hip/hip_runtime.h>

// AP (average precision @ IoU 0.5/0.75) for B=256, N=4000, G=50.
// Strategy: greedy TP matching -> <=50 TPs per (batch,thr); exact stable
// descending-sort ranks of TPs via 1024-bucket counting sort of the 1.024M
// confidences; AP from TP ranks only.
//
// R1: pos_kernel 390us (latency-bound global loop) -> LDS+int4 broadcast.
// R2-R4: tp_kernel stuck ~145us: 1M device-scope hist atomics (32MB TCC
//     write traffic, ~8.4G atomics/s). -> zero-global-atomic design.
// R5: crashed (tp LDS 84KB > 64KB; ws 20MB). R6: resized, 423us.
// R7: rank one-wave-per-slot (195 -> ~0); 260us. pos_kernel now top: 90us,
//     100 blocks only, LDS-broadcast-pipe bound.
// R8: pos split: pos1 = 4 t's per lane x K=16 u-tiles x 416 blocks
//     (4x fewer broadcast reads, 16x more blocks), partials in pcount
//     (aliases dead sPair region); pos2 sums 16 partials + scatters.

#define B_ 256
#define N_ 4000
#define G_ 50
#define M_ (B_ * N_)        // 1,024,000 proposals total
#define NL_ (B_ * G_)       // 12,800 labels total (= n_labels)
#define NBKT 1024
#define KP 16               // u-tile splits in pos1
#define TILE (NL_ / KP)     // 800

__device__ __forceinline__ unsigned bucket_of(float c) {
    unsigned b = (unsigned)(c * 1024.0f);
    return b > (NBKT - 1) ? (NBKT - 1) : b;
}

// ---- Phase 1: greedy matching (both thr) + LDS-private histogram. ---------
__global__ __launch_bounds__(1024) void tp_kernel(
    const float* __restrict__ seg,    // [B,N,2]
    const float* __restrict__ gts,    // [B,G,2]
    const float* __restrict__ conf,   // [B,N]
    int* __restrict__ tpIdx,          // [2][NL_], slots [b*50, b*50+cnt)
    int* __restrict__ cnt,            // [2][B_]
    unsigned short* __restrict__ pbh) // [B_][NBKT] per-batch histogram
{
    const int tid  = threadIdx.x;
    const int lane = tid & 63;
    const int wv   = tid >> 6;            // wave id 0..15
    const int b    = blockIdx.x;

    __shared__ float2 gtl[G_];                           // 400 B
    __shared__ unsigned long long cand[2][G_][64];       // 51.2 KiB
    __shared__ unsigned hls[NBKT];                       // 4 KiB
    __shared__ int lcnt[2];                              // total 55.7 KiB < 64 KiB

    if (tid < NBKT) hls[tid] = 0u;
    if (tid < G_) gtl[tid] = ((const float2*)gts)[b * G_ + tid];
    if (tid < 2) lcnt[tid] = 0;
    __syncthreads();

    // LDS-private histogram of this batch's 4000 scores
    const float* cb = conf + (size_t)b * N_;
    #pragma unroll
    for (int s = 0; s < 4; ++s) {
        int n = s * 1024 + tid;
        if (n < N_) atomicAdd(&hls[bucket_of(cb[n])], 1u);
    }

    // Phase A: one IoU per (proposal, gt), ballot into both thresholds' masks.
    const float2* sb = (const float2*)(seg + (size_t)b * (N_ * 2));
    #pragma unroll
    for (int s = 0; s < 4; ++s) {
        int n = s * 1024 + tid;
        float pmin, pmax;
        if (n < N_) { float2 v = sb[n]; pmin = v.x; pmax = v.y; }
        else { pmin = 1e9f; pmax = 1e9f; }   // sentinel -> iou 0
        const int q = s * 16 + wv;           // qword covering this wave's 64 props
        float plen = pmax - pmin;
        for (int g = 0; g < G_; ++g) {
            float2 gt = gtl[g];              // LDS broadcast
            float inter = fmaxf(fminf(pmax, gt.y) - fmaxf(pmin, gt.x), 0.0f);
            float uni = plen + (gt.y - gt.x) - inter;   // same op order as ref
            float iou = inter / uni;
            unsigned long long m0 = __ballot(iou > 0.5f);
            unsigned long long m1 = __ballot(iou > 0.75f);
            if (lane == 0) { cand[0][g][q] = m0; cand[1][g][q] = m1; }
        }
    }
    __syncthreads();   // cand complete + hist complete

    // write per-batch histogram row (u16; per-batch bin count <= 4000)
    if (tid < NBKT) pbh[(size_t)b * NBKT + tid] = (unsigned short)hls[tid];

    // Phase B: wave 0 -> thr 0.5, wave 1 -> thr 0.75. Greedy via ballot+ffs.
    if (wv < 2) {
        const int thr_i = wv;
        unsigned long long used = 0ull;      // proposals [lane*64, lane*64+64)
        for (int g = 0; g < G_; ++g) {
            unsigned long long c = cand[thr_i][g][lane] & ~used;
            unsigned long long ball = __ballot(c != 0ull);
            if (ball) {
                int fl = __ffsll(ball) - 1;  // lowest lane = lowest proposal range
                if (lane == fl) used |= (c & (0ull - c));   // lowest set bit
            }
        }
        int cpop = __popcll(used);
        if (cpop) {
            int j = atomicAdd(&lcnt[thr_i], cpop);   // LDS atomic, block-local
            unsigned long long u = used;
            while (u) {
                int bit = __ffsll(u) - 1;
                u &= u - 1;
                tpIdx[thr_i * NL_ + b * G_ + j++] = b * N_ + lane * 64 + bit;
            }
        }
    }
    __syncthreads();
    if (tid < 2) cnt[tid * B_ + b] = lcnt[tid];
}

// ---- S1: in-place per-(batch,bin) exclusive prefix over batches + totals --
__global__ __launch_bounds__(256) void s1_kernel(
    unsigned short* __restrict__ pbh,        // [B_][NBKT] -> becomes prefix
    unsigned* __restrict__ total)            // [NBKT]
{
    int bin = blockIdx.x * 256 + threadIdx.x;
    unsigned run = 0;
    for (int b = 0; b < B_; ++b) {           // coalesced across threads
        size_t o = (size_t)b * NBKT + bin;
        unsigned v = pbh[o];
        pbh[o] = (unsigned short)run;
        run += v;
    }
    total[bin] = run;
}

// ---- S2: exclusive scan of 1024 bin totals, single block ------------------
__global__ __launch_bounds__(1024) void s2_kernel(
    const unsigned* __restrict__ total, unsigned* __restrict__ binStart)
{
    __shared__ unsigned part[1024];
    int t = threadIdx.x;
    part[t] = total[t];
    __syncthreads();
    for (int off = 1; off < 1024; off <<= 1) {   // inclusive Hillis-Steele
        unsigned add = (t >= off) ? part[t - off] : 0u;
        unsigned v = part[t];
        __syncthreads();
        part[t] = v + add;
        __syncthreads();
    }
    binStart[t] = (t == 0) ? 0u : part[t - 1];
}

// ---- Scatter: deterministic positions, zero global atomics ----------------
__global__ __launch_bounds__(1024) void scatter_kernel(
    const float* __restrict__ conf,
    const unsigned short* __restrict__ pbh,  // now the exclusive prefix
    const unsigned* __restrict__ binStart,
    float2* __restrict__ sPair)
{
    __shared__ unsigned baseB[NBKT];   // 4 KiB
    __shared__ unsigned lofs[NBKT];    // 4 KiB
    const int tid = threadIdx.x;
    const int b = blockIdx.x;
    if (tid < NBKT) {
        baseB[tid] = binStart[tid] + pbh[(size_t)b * NBKT + tid];
        lofs[tid] = 0u;
    }
    __syncthreads();
    const float* cb = conf + (size_t)b * N_;
    #pragma unroll
    for (int s = 0; s < 4; ++s) {
        int n = s * 1024 + tid;
        if (n < N_) {
            float c = cb[n];
            unsigned bin = bucket_of(c);
            unsigned lo = atomicAdd(&lofs[bin], 1u);   // LDS atomic
            sPair[baseB[bin] + lo] = make_float2(c, __uint_as_float((unsigned)(b * N_ + n)));
        }
    }
}

// ---- Rank: one WAVE per TP slot; lanes stride the bucket ------------------
__global__ __launch_bounds__(256) void rank_kernel(
    const float* __restrict__ conf,
    const int* __restrict__ tpIdx,
    const int* __restrict__ cnt,
    const unsigned* __restrict__ total,
    const unsigned* __restrict__ binStart,
    const float2* __restrict__ sPair,
    int* __restrict__ tpRank)
{
    const int lane = threadIdx.x & 63;
    const int w = (blockIdx.x << 2) | (threadIdx.x >> 6);   // global wave id
    if (w >= 2 * NL_) return;
    const int thr_i = w / NL_;
    const int t = w - thr_i * NL_;
    const int batch = t / G_;
    const int j = t - batch * G_;

    if (j < cnt[thr_i * B_ + batch]) {
        int e = tpIdx[thr_i * NL_ + t];
        float c = conf[e];
        unsigned bin = bucket_of(c);
        unsigned lo = binStart[bin], n = total[bin];
        int r = M_ - (int)lo - (int)n;   // strictly-better buckets
        for (unsigned base = 0; base < n; base += 64) {
            unsigned k = base + lane;
            bool pred = false;
            if (k < n) {
                float2 p = sPair[lo + k];
                unsigned si = __float_as_uint(p.y);
                pred = (p.x > c) || (p.x == c && si < (unsigned)e);
            }
            r += (int)__popcll(__ballot(pred));   // wave-uniform partial sum
        }
        if (lane == 0) tpRank[thr_i * NL_ + t] = r;
    } else {
        if (lane == 0) tpRank[thr_i * NL_ + t] = M_ + t;   // distinct sentinel
    }
}

// ---- Pos1: partial counts, 4 t's per lane, K=16 u-tiles -------------------
__global__ __launch_bounds__(256) void pos1_kernel(
    const int* __restrict__ tpRank,
    int* __restrict__ pcount)          // [2][KP][NL_]
{
    __shared__ alignas(16) int tile[TILE];
    const int k = blockIdx.y, thr_i = blockIdx.z;
    const int* base = tpRank + thr_i * NL_;
    for (int i = threadIdx.x; i < TILE; i += 256)
        tile[i] = base[k * TILE + i];
    __syncthreads();

    const int t0 = blockIdx.x * 1024 + threadIdx.x;
    int r[4], c[4] = {0, 0, 0, 0};
    #pragma unroll
    for (int j = 0; j < 4; ++j) {
        int t = t0 + j * 256;
        r[j] = (t < NL_) ? base[t] : -1;   // ranks >= 0, so c stays 0
    }
    const int4* l4 = (const int4*)tile;
    #pragma unroll 4
    for (int i = 0; i < TILE / 4; ++i) {   // wave-uniform -> LDS broadcast
        int4 v = l4[i];
        #pragma unroll
        for (int j = 0; j < 4; ++j)
            c[j] += (v.x < r[j]) + (v.y < r[j]) + (v.z < r[j]) + (v.w < r[j]);
    }
    #pragma unroll
    for (int j = 0; j < 4; ++j) {
        int t = t0 + j * 256;
        if (t < NL_) pcount[(thr_i * KP + k) * NL_ + t] = c[j];
    }
}

// ---- Pos2: sum partials, scatter sorted ranks -----------------------------
__global__ __launch_bounds__(256) void pos2_kernel(
    const int* __restrict__ tpRank,
    const int* __restrict__ pcount,
    int* __restrict__ sortedRank)
{
    int gt = blockIdx.x * 256 + threadIdx.x;   // 0 .. 2*NL_-1
    int thr_i = gt / NL_;
    int t = gt - thr_i * NL_;
    int p = 0;
    #pragma unroll
    for (int k = 0; k < KP; ++k)
        p += pcount[(thr_i * KP + k) * NL_ + t];   // coalesced per k
    sortedRank[thr_i * NL_ + p] = tpRank[thr_i * NL_ + t];   // bijection
}

// ---- AP from sorted TP ranks. One block per threshold. --------------------
__global__ __launch_bounds__(1024) void ap_kernel(const int* __restrict__ sortedRank,
                                                  float* __restrict__ out)
{
    const int C = 13;   // 1024*13 = 13312 >= NL_
    int thr_i = blockIdx.x;
    int t = threadIdx.x;
    const int* sr = sortedRank + thr_i * NL_;

    float pr[C]; int rk[C];
    #pragma unroll
    for (int k = 0; k < C; ++k) {
        int i = t * C + k;
        rk[k] = (i < NL_) ? sr[i] : 0x7FFFFFFF;
        pr[k] = (rk[k] < M_) ? (float)(i + 1) / (float)(rk[k] + 1) : -1.0f;
    }
    float suf[C];
    float run = -1.0f;
    #pragma unroll
    for (int k = C - 1; k >= 0; --k) { run = fmaxf(run, pr[k]); suf[k] = run; }

    __shared__ float cmax[1024];
    cmax[t] = run;
    __syncthreads();
    for (int off = 1; off < 1024; off <<= 1) {   // inclusive suffix-max scan
        float v = cmax[t];
        float o = (t + off < 1024) ? cmax[t + off] : -1.0f;
        __syncthreads();
        cmax[t] = fmaxf(v, o);
        __syncthreads();
    }
    float follow = (t + 1 < 1024) ? cmax[t + 1] : -1.0f;

    double acc = 0.0;
    #pragma unroll
    for (int k = 0; k < C; ++k) {
        int i = t * C + k;
        if (rk[k] >= 1 && rk[k] < M_) {   // global rank 0 excluded by ref curve
            float smax = fmaxf(suf[k], follow);
            float rhi = (float)(i + 1) / 12800.0f;
            float rlo = (float)i / 12800.0f;
            acc += (double)((rhi - rlo) * smax);
        }
    }
    __shared__ double red[1024];
    red[t] = acc;
    __syncthreads();
    for (int off = 512; off >= 1; off >>= 1) {
        if (t < off) red[t] += red[t + off];
        __syncthreads();
    }
    if (t == 0) out[thr_i] = (float)red[0];
}

extern "C" void kernel_launch(void* const* d_in, const int* in_sizes, int n_in,
                              void* d_out, int out_size, void* d_ws, size_t ws_size,
                              hipStream_t stream) {
    const float* scores = (const float*)d_in[0];   // [B,N]
    const float* seg    = (const float*)d_in[1];   // [B,N,2]
    const float* gts    = (const float*)d_in[2];   // [B,G,2]
    float* out = (float*)d_out;

    char* p = (char*)d_ws;
    int*            cnt        = (int*)p;             p += 4096;                  // 2KB used
    int*            tpIdx      = (int*)p;             p += 2 * NL_ * 4;           // 100 KB
    int*            tpRank     = (int*)p;             p += 2 * NL_ * 4;           // 100 KB
    int*            sortedRank = (int*)p;             p += 2 * NL_ * 4;           // 100 KB
    unsigned*       total      = (unsigned*)p;        p += NBKT * 4;              // 4 KB
    unsigned*       binStart   = (unsigned*)p;        p += NBKT * 4;              // 4 KB
    unsigned short* pbh        = (unsigned short*)p;  p += (size_t)B_ * NBKT * 2; // 512 KB
    float2*         sPair      = (float2*)p;          p += (size_t)M_ * 8;        // 8 MB
    int*            pcount     = (int*)sPair;   // aliases sPair (dead after rank)
    (void)ws_size; (void)in_sizes; (void)n_in; (void)out_size;     // total ~9.04 MB

    // No memset: every workspace word read downstream is written upstream.
    tp_kernel<<<B_, 1024, 0, stream>>>(seg, gts, scores, tpIdx, cnt, pbh);
    s1_kernel<<<NBKT / 256, 256, 0, stream>>>(pbh, total);
    s2_kernel<<<1, 1024, 0, stream>>>(total, binStart);
    scatter_kernel<<<B_, 1024, 0, stream>>>(scores, pbh, binStart, sPair);
    rank_kernel<<<(2 * NL_ + 3) / 4, 256, 0, stream>>>(scores, tpIdx, cnt,
                                                       total, binStart, sPair, tpRank);
    pos1_kernel<<<dim3(13, KP, 2), 256, 0, stream>>>(tpRank, pcount);
    pos2_kernel<<<2 * NL_ / 256, 256, 0, stream>>>(tpRank, pcount, sortedRank);
    ap_kernel<<<2, 1024, 0, stream>>>(sortedRank, out);
}

// Round 9
// 201.330 us; speedup vs baseline: 2.1552x; 1.0130x over previous
//
#include <hip/hip_runtime.h>

// AP (average precision @ IoU 0.5/0.75) for B=256, N=4000, G=50.
// Strategy: greedy TP matching -> <=50 TPs per (batch,thr); exact stable
// descending-sort ranks of TPs via 1024-bucket counting sort of the 1.024M
// confidences; AP from TP ranks only.
//
// R1: pos_kernel 390us (latency-bound global loop) -> LDS+int4 broadcast.
// R2-R4: tp_kernel stuck ~145us: 1M device-scope hist atomics (32MB TCC
//     write traffic, ~8.4G atomics/s). -> zero-global-atomic design.
// R5: crashed (tp LDS 84KB > 64KB; ws 20MB). R6: resized, 423us.
// R7: rank one-wave-per-slot (195 -> ~0); 260us. R8: pos1/pos2 split
//     (90 -> ~15); 204us. tp_kernel now top: 52us, ~50 VALU instr/IoU
//     (only ~17 essential) -- per-iter gtl ds_read + glen recompute +
//     400 exec-masked cand-write branches.
// R9: tp Phase A loop swap: g OUTER, 4 slots inner. Props in 12 regs,
//     gtl read once per g (ds_read 200->50/thread), glen hoisted,
//     8 cand stores batched under one lane==0 branch per g.

#define B_ 256
#define N_ 4000
#define G_ 50
#define M_ (B_ * N_)        // 1,024,000 proposals total
#define NL_ (B_ * G_)       // 12,800 labels total (= n_labels)
#define NBKT 1024
#define KP 16               // u-tile splits in pos1
#define TILE (NL_ / KP)     // 800

__device__ __forceinline__ unsigned bucket_of(float c) {
    unsigned b = (unsigned)(c * 1024.0f);
    return b > (NBKT - 1) ? (NBKT - 1) : b;
}

// ---- Phase 1: greedy matching (both thr) + LDS-private histogram. ---------
__global__ __launch_bounds__(1024) void tp_kernel(
    const float* __restrict__ seg,    // [B,N,2]
    const float* __restrict__ gts,    // [B,G,2]
    const float* __restrict__ conf,   // [B,N]
    int* __restrict__ tpIdx,          // [2][NL_], slots [b*50, b*50+cnt)
    int* __restrict__ cnt,            // [2][B_]
    unsigned short* __restrict__ pbh) // [B_][NBKT] per-batch histogram
{
    const int tid  = threadIdx.x;
    const int lane = tid & 63;
    const int wv   = tid >> 6;            // wave id 0..15
    const int b    = blockIdx.x;

    __shared__ float2 gtl[G_];                           // 400 B
    __shared__ unsigned long long cand[2][G_][64];       // 51.2 KiB
    __shared__ unsigned hls[NBKT];                       // 4 KiB
    __shared__ int lcnt[2];                              // total 55.7 KiB < 64 KiB

    if (tid < NBKT) hls[tid] = 0u;
    if (tid < G_) gtl[tid] = ((const float2*)gts)[b * G_ + tid];
    if (tid < 2) lcnt[tid] = 0;
    __syncthreads();

    // LDS-private histogram of this batch's 4000 scores
    const float* cb = conf + (size_t)b * N_;
    #pragma unroll
    for (int s = 0; s < 4; ++s) {
        int n = s * 1024 + tid;
        if (n < N_) atomicAdd(&hls[bucket_of(cb[n])], 1u);
    }

    // Phase A (g outer, slots inner): props in registers, gt read once per g.
    const float2* sb = (const float2*)(seg + (size_t)b * (N_ * 2));
    float pmin[4], pmax[4], plen[4];
    #pragma unroll
    for (int s = 0; s < 4; ++s) {
        int n = s * 1024 + tid;
        if (n < N_) { float2 v = sb[n]; pmin[s] = v.x; pmax[s] = v.y; }
        else { pmin[s] = 1e9f; pmax[s] = 1e9f; }   // sentinel -> iou 0
        plen[s] = pmax[s] - pmin[s];               // == ref's (amax - amin)
    }
    for (int g = 0; g < G_; ++g) {
        float2 gt = gtl[g];                        // one LDS broadcast per g
        float glen = gt.y - gt.x;
        unsigned long long m0[4], m1[4];
        #pragma unroll
        for (int s = 0; s < 4; ++s) {
            float inter = fmaxf(fminf(pmax[s], gt.y) - fmaxf(pmin[s], gt.x), 0.0f);
            float uni = plen[s] + glen - inter;    // same op order as ref
            float iou = inter / uni;               // exact IEEE divide
            m0[s] = __ballot(iou > 0.5f);
            m1[s] = __ballot(iou > 0.75f);
        }
        if (lane == 0) {                           // one branch, 8 stores
            #pragma unroll
            for (int s = 0; s < 4; ++s) {
                cand[0][g][s * 16 + wv] = m0[s];
                cand[1][g][s * 16 + wv] = m1[s];
            }
        }
    }
    __syncthreads();   // cand complete + hist complete

    // write per-batch histogram row (u16; per-batch bin count <= 4000)
    if (tid < NBKT) pbh[(size_t)b * NBKT + tid] = (unsigned short)hls[tid];

    // Phase B: wave 0 -> thr 0.5, wave 1 -> thr 0.75. Greedy via ballot+ffs.
    if (wv < 2) {
        const int thr_i = wv;
        unsigned long long used = 0ull;      // proposals [lane*64, lane*64+64)
        for (int g = 0; g < G_; ++g) {
            unsigned long long c = cand[thr_i][g][lane] & ~used;
            unsigned long long ball = __ballot(c != 0ull);
            if (ball) {
                int fl = __ffsll(ball) - 1;  // lowest lane = lowest proposal range
                if (lane == fl) used |= (c & (0ull - c));   // lowest set bit
            }
        }
        int cpop = __popcll(used);
        if (cpop) {
            int j = atomicAdd(&lcnt[thr_i], cpop);   // LDS atomic, block-local
            unsigned long long u = used;
            while (u) {
                int bit = __ffsll(u) - 1;
                u &= u - 1;
                tpIdx[thr_i * NL_ + b * G_ + j++] = b * N_ + lane * 64 + bit;
            }
        }
    }
    __syncthreads();
    if (tid < 2) cnt[tid * B_ + b] = lcnt[tid];
}

// ---- S1: in-place per-(batch,bin) exclusive prefix over batches + totals --
__global__ __launch_bounds__(256) void s1_kernel(
    unsigned short* __restrict__ pbh,        // [B_][NBKT] -> becomes prefix
    unsigned* __restrict__ total)            // [NBKT]
{
    int bin = blockIdx.x * 256 + threadIdx.x;
    unsigned run = 0;
    for (int b = 0; b < B_; ++b) {           // coalesced across threads
        size_t o = (size_t)b * NBKT + bin;
        unsigned v = pbh[o];
        pbh[o] = (unsigned short)run;
        run += v;
    }
    total[bin] = run;
}

// ---- S2: exclusive scan of 1024 bin totals, single block ------------------
__global__ __launch_bounds__(1024) void s2_kernel(
    const unsigned* __restrict__ total, unsigned* __restrict__ binStart)
{
    __shared__ unsigned part[1024];
    int t = threadIdx.x;
    part[t] = total[t];
    __syncthreads();
    for (int off = 1; off < 1024; off <<= 1) {   // inclusive Hillis-Steele
        unsigned add = (t >= off) ? part[t - off] : 0u;
        unsigned v = part[t];
        __syncthreads();
        part[t] = v + add;
        __syncthreads();
    }
    binStart[t] = (t == 0) ? 0u : part[t - 1];
}

// ---- Scatter: deterministic positions, zero global atomics ----------------
__global__ __launch_bounds__(1024) void scatter_kernel(
    const float* __restrict__ conf,
    const unsigned short* __restrict__ pbh,  // now the exclusive prefix
    const unsigned* __restrict__ binStart,
    float2* __restrict__ sPair)
{
    __shared__ unsigned baseB[NBKT];   // 4 KiB
    __shared__ unsigned lofs[NBKT];    // 4 KiB
    const int tid = threadIdx.x;
    const int b = blockIdx.x;
    if (tid < NBKT) {
        baseB[tid] = binStart[tid] + pbh[(size_t)b * NBKT + tid];
        lofs[tid] = 0u;
    }
    __syncthreads();
    const float* cb = conf + (size_t)b * N_;
    #pragma unroll
    for (int s = 0; s < 4; ++s) {
        int n = s * 1024 + tid;
        if (n < N_) {
            float c = cb[n];
            unsigned bin = bucket_of(c);
            unsigned lo = atomicAdd(&lofs[bin], 1u);   // LDS atomic
            sPair[baseB[bin] + lo] = make_float2(c, __uint_as_float((unsigned)(b * N_ + n)));
        }
    }
}

// ---- Rank: one WAVE per TP slot; lanes stride the bucket ------------------
__global__ __launch_bounds__(256) void rank_kernel(
    const float* __restrict__ conf,
    const int* __restrict__ tpIdx,
    const int* __restrict__ cnt,
    const unsigned* __restrict__ total,
    const unsigned* __restrict__ binStart,
    const float2* __restrict__ sPair,
    int* __restrict__ tpRank)
{
    const int lane = threadIdx.x & 63;
    const int w = (blockIdx.x << 2) | (threadIdx.x >> 6);   // global wave id
    if (w >= 2 * NL_) return;
    const int thr_i = w / NL_;
    const int t = w - thr_i * NL_;
    const int batch = t / G_;
    const int j = t - batch * G_;

    if (j < cnt[thr_i * B_ + batch]) {
        int e = tpIdx[thr_i * NL_ + t];
        float c = conf[e];
        unsigned bin = bucket_of(c);
        unsigned lo = binStart[bin], n = total[bin];
        int r = M_ - (int)lo - (int)n;   // strictly-better buckets
        for (unsigned base = 0; base < n; base += 64) {
            unsigned k = base + lane;
            bool pred = false;
            if (k < n) {
                float2 p = sPair[lo + k];
                unsigned si = __float_as_uint(p.y);
                pred = (p.x > c) || (p.x == c && si < (unsigned)e);
            }
            r += (int)__popcll(__ballot(pred));   // wave-uniform partial sum
        }
        if (lane == 0) tpRank[thr_i * NL_ + t] = r;
    } else {
        if (lane == 0) tpRank[thr_i * NL_ + t] = M_ + t;   // distinct sentinel
    }
}

// ---- Pos1: partial counts, 4 t's per lane, K=16 u-tiles -------------------
__global__ __launch_bounds__(256) void pos1_kernel(
    const int* __restrict__ tpRank,
    int* __restrict__ pcount)          // [2][KP][NL_]
{
    __shared__ alignas(16) int tile[TILE];
    const int k = blockIdx.y, thr_i = blockIdx.z;
    const int* base = tpRank + thr_i * NL_;
    for (int i = threadIdx.x; i < TILE; i += 256)
        tile[i] = base[k * TILE + i];
    __syncthreads();

    const int t0 = blockIdx.x * 1024 + threadIdx.x;
    int r[4], c[4] = {0, 0, 0, 0};
    #pragma unroll
    for (int j = 0; j < 4; ++j) {
        int t = t0 + j * 256;
        r[j] = (t < NL_) ? base[t] : -1;   // ranks >= 0, so c stays 0
    }
    const int4* l4 = (const int4*)tile;
    #pragma unroll 4
    for (int i = 0; i < TILE / 4; ++i) {   // wave-uniform -> LDS broadcast
        int4 v = l4[i];
        #pragma unroll
        for (int j = 0; j < 4; ++j)
            c[j] += (v.x < r[j]) + (v.y < r[j]) + (v.z < r[j]) + (v.w < r[j]);
    }
    #pragma unroll
    for (int j = 0; j < 4; ++j) {
        int t = t0 + j * 256;
        if (t < NL_) pcount[(thr_i * KP + k) * NL_ + t] = c[j];
    }
}

// ---- Pos2: sum partials, scatter sorted ranks -----------------------------
__global__ __launch_bounds__(256) void pos2_kernel(
    const int* __restrict__ tpRank,
    const int* __restrict__ pcount,
    int* __restrict__ sortedRank)
{
    int gt = blockIdx.x * 256 + threadIdx.x;   // 0 .. 2*NL_-1
    int thr_i = gt / NL_;
    int t = gt - thr_i * NL_;
    int p = 0;
    #pragma unroll
    for (int k = 0; k < KP; ++k)
        p += pcount[(thr_i * KP + k) * NL_ + t];   // coalesced per k
    sortedRank[thr_i * NL_ + p] = tpRank[thr_i * NL_ + t];   // bijection
}

// ---- AP from sorted TP ranks. One block per threshold. --------------------
__global__ __launch_bounds__(1024) void ap_kernel(const int* __restrict__ sortedRank,
                                                  float* __restrict__ out)
{
    const int C = 13;   // 1024*13 = 13312 >= NL_
    int thr_i = blockIdx.x;
    int t = threadIdx.x;
    const int* sr = sortedRank + thr_i * NL_;

    float pr[C]; int rk[C];
    #pragma unroll
    for (int k = 0; k < C; ++k) {
        int i = t * C + k;
        rk[k] = (i < NL_) ? sr[i] : 0x7FFFFFFF;
        pr[k] = (rk[k] < M_) ? (float)(i + 1) / (float)(rk[k] + 1) : -1.0f;
    }
    float suf[C];
    float run = -1.0f;
    #pragma unroll
    for (int k = C - 1; k >= 0; --k) { run = fmaxf(run, pr[k]); suf[k] = run; }

    __shared__ float cmax[1024];
    cmax[t] = run;
    __syncthreads();
    for (int off = 1; off < 1024; off <<= 1) {   // inclusive suffix-max scan
        float v = cmax[t];
        float o = (t + off < 1024) ? cmax[t + off] : -1.0f;
        __syncthreads();
        cmax[t] = fmaxf(v, o);
        __syncthreads();
    }
    float follow = (t + 1 < 1024) ? cmax[t + 1] : -1.0f;

    double acc = 0.0;
    #pragma unroll
    for (int k = 0; k < C; ++k) {
        int i = t * C + k;
        if (rk[k] >= 1 && rk[k] < M_) {   // global rank 0 excluded by ref curve
            float smax = fmaxf(suf[k], follow);
            float rhi = (float)(i + 1) / 12800.0f;
            float rlo = (float)i / 12800.0f;
            acc += (double)((rhi - rlo) * smax);
        }
    }
    __shared__ double red[1024];
    red[t] = acc;
    __syncthreads();
    for (int off = 512; off >= 1; off >>= 1) {
        if (t < off) red[t] += red[t + off];
        __syncthreads();
    }
    if (t == 0) out[thr_i] = (float)red[0];
}

extern "C" void kernel_launch(void* const* d_in, const int* in_sizes, int n_in,
                              void* d_out, int out_size, void* d_ws, size_t ws_size,
                              hipStream_t stream) {
    const float* scores = (const float*)d_in[0];   // [B,N]
    const float* seg    = (const float*)d_in[1];   // [B,N,2]
    const float* gts    = (const float*)d_in[2];   // [B,G,2]
    float* out = (float*)d_out;

    char* p = (char*)d_ws;
    int*            cnt        = (int*)p;             p += 4096;                  // 2KB used
    int*            tpIdx      = (int*)p;             p += 2 * NL_ * 4;           // 100 KB
    int*            tpRank     = (int*)p;             p += 2 * NL_ * 4;           // 100 KB
    int*            sortedRank = (int*)p;             p += 2 * NL_ * 4;           // 100 KB
    unsigned*       total      = (unsigned*)p;        p += NBKT * 4;              // 4 KB
    unsigned*       binStart   = (unsigned*)p;        p += NBKT * 4;              // 4 KB
    unsigned short* pbh        = (unsigned short*)p;  p += (size_t)B_ * NBKT * 2; // 512 KB
    float2*         sPair      = (float2*)p;          p += (size_t)M_ * 8;        // 8 MB
    int*            pcount     = (int*)sPair;   // aliases sPair (dead after rank)
    (void)ws_size; (void)in_sizes; (void)n_in; (void)out_size;     // total ~9.04 MB

    // No memset: every workspace word read downstream is written upstream.
    tp_kernel<<<B_, 1024, 0, stream>>>(seg, gts, scores, tpIdx, cnt, pbh);
    s1_kernel<<<NBKT / 256, 256, 0, stream>>>(pbh, total);
    s2_kernel<<<1, 1024, 0, stream>>>(total, binStart);
    scatter_kernel<<<B_, 1024, 0, stream>>>(scores, pbh, binStart, sPair);
    rank_kernel<<<(2 * NL_ + 3) / 4, 256, 0, stream>>>(scores, tpIdx, cnt,
                                                       total, binStart, sPair, tpRank);
    pos1_kernel<<<dim3(13, KP, 2), 256, 0, stream>>>(tpRank, pcount);
    pos2_kernel<<<2 * NL_ / 256, 256, 0, stream>>>(tpRank, pcount, sortedRank);
    ap_kernel<<<2, 1024, 0, stream>>>(sortedRank, out);
}

// Round 10
// 191.374 us; speedup vs baseline: 2.2673x; 1.0520x over previous
//
#include <hip/hip_runtime.h>

// AP (average precision @ IoU 0.5/0.75) for B=256, N=4000, G=50.
// Strategy: greedy TP matching -> <=50 TPs per (batch,thr); exact stable
// descending-sort ranks of TPs via 1024-bucket counting sort of the 1.024M
// confidences; AP from TP ranks only.
//
// R1: pos_kernel 390us (latency-bound global loop) -> LDS+int4 broadcast.
// R2-R4: tp_kernel stuck ~145us: 1M device-scope hist atomics. -> zero-
//     global-atomic design. R5: crashed (LDS 84KB; ws 20MB). R6: 423us.
// R7: rank one-wave-per-slot (195 -> ~0); 260us. R8: pos1/pos2 split; 204us.
// R9: g-outer loop swap ~neutral (52->50us): not LDS-read-bound. 44 VALU
//     instr/IoU; the f32 IEEE divide chain (div_scale/rcp/5xfma/fixup,
//     serial latency) dominates at only 16 waves/CU.
// R10: divide eliminated BIT-EXACTLY: fl(inter/uni) > thr  <=>
//     (double)inter > (thr + 2^-25) * (double)uni   [uni>0 always; M has
//     25 sig bits x uni 24 bits = 49-bit product, exact in double; RNE tie
//     at midpoint rounds to even = thr]. 2 cvt + 2 mul_f64 + 2 cmp_f64
//     replace the divide chain.

#define B_ 256
#define N_ 4000
#define G_ 50
#define M_ (B_ * N_)        // 1,024,000 proposals total
#define NL_ (B_ * G_)       // 12,800 labels total (= n_labels)
#define NBKT 1024
#define KP 16               // u-tile splits in pos1
#define TILE (NL_ / KP)     // 800

// exact decision thresholds: thr + 2^-25
#define M0_ 0x1.000001p-1   // 0.5  + 2^-25
#define M1_ 0x1.800001p-1   // 0.75 + 2^-25

__device__ __forceinline__ unsigned bucket_of(float c) {
    unsigned b = (unsigned)(c * 1024.0f);
    return b > (NBKT - 1) ? (NBKT - 1) : b;
}

// ---- Phase 1: greedy matching (both thr) + LDS-private histogram. ---------
__global__ __launch_bounds__(1024) void tp_kernel(
    const float* __restrict__ seg,    // [B,N,2]
    const float* __restrict__ gts,    // [B,G,2]
    const float* __restrict__ conf,   // [B,N]
    int* __restrict__ tpIdx,          // [2][NL_], slots [b*50, b*50+cnt)
    int* __restrict__ cnt,            // [2][B_]
    unsigned short* __restrict__ pbh) // [B_][NBKT] per-batch histogram
{
    const int tid  = threadIdx.x;
    const int lane = tid & 63;
    const int wv   = tid >> 6;            // wave id 0..15
    const int b    = blockIdx.x;

    __shared__ float2 gtl[G_];                           // 400 B
    __shared__ unsigned long long cand[2][G_][64];       // 51.2 KiB
    __shared__ unsigned hls[NBKT];                       // 4 KiB
    __shared__ int lcnt[2];                              // total 55.7 KiB < 64 KiB

    if (tid < NBKT) hls[tid] = 0u;
    if (tid < G_) gtl[tid] = ((const float2*)gts)[b * G_ + tid];
    if (tid < 2) lcnt[tid] = 0;
    __syncthreads();

    // LDS-private histogram of this batch's 4000 scores
    const float* cb = conf + (size_t)b * N_;
    #pragma unroll
    for (int s = 0; s < 4; ++s) {
        int n = s * 1024 + tid;
        if (n < N_) atomicAdd(&hls[bucket_of(cb[n])], 1u);
    }

    // Phase A (g outer, slots inner): props in registers, gt read once per g.
    const float2* sb = (const float2*)(seg + (size_t)b * (N_ * 2));
    float pmin[4], pmax[4], plen[4];
    #pragma unroll
    for (int s = 0; s < 4; ++s) {
        int n = s * 1024 + tid;
        if (n < N_) { float2 v = sb[n]; pmin[s] = v.x; pmax[s] = v.y; }
        else { pmin[s] = 1e9f; pmax[s] = 1e9f; }   // sentinel -> iou 0
        plen[s] = pmax[s] - pmin[s];               // == ref's (amax - amin)
    }
    for (int g = 0; g < G_; ++g) {
        float2 gt = gtl[g];                        // one LDS broadcast per g
        float glen = gt.y - gt.x;
        unsigned long long m0[4], m1[4];
        #pragma unroll
        for (int s = 0; s < 4; ++s) {
            float inter = fmaxf(fminf(pmax[s], gt.y) - fmaxf(pmin[s], gt.x), 0.0f);
            float uni = plen[s] + glen - inter;    // f32, same op order as ref
            double di = (double)inter;             // exact
            double du = (double)uni;               // exact; uni > 0 always
            m0[s] = __ballot(di > M0_ * du);       // == fl(inter/uni) > 0.5f
            m1[s] = __ballot(di > M1_ * du);       // == fl(inter/uni) > 0.75f
        }
        if (lane == 0) {                           // one branch, 8 stores
            #pragma unroll
            for (int s = 0; s < 4; ++s) {
                cand[0][g][s * 16 + wv] = m0[s];
                cand[1][g][s * 16 + wv] = m1[s];
            }
        }
    }
    __syncthreads();   // cand complete + hist complete

    // write per-batch histogram row (u16; per-batch bin count <= 4000)
    if (tid < NBKT) pbh[(size_t)b * NBKT + tid] = (unsigned short)hls[tid];

    // Phase B: wave 0 -> thr 0.5, wave 1 -> thr 0.75. Greedy via ballot+ffs.
    if (wv < 2) {
        const int thr_i = wv;
        unsigned long long used = 0ull;      // proposals [lane*64, lane*64+64)
        for (int g = 0; g < G_; ++g) {
            unsigned long long c = cand[thr_i][g][lane] & ~used;
            unsigned long long ball = __ballot(c != 0ull);
            if (ball) {
                int fl = __ffsll(ball) - 1;  // lowest lane = lowest proposal range
                if (lane == fl) used |= (c & (0ull - c));   // lowest set bit
            }
        }
        int cpop = __popcll(used);
        if (cpop) {
            int j = atomicAdd(&lcnt[thr_i], cpop);   // LDS atomic, block-local
            unsigned long long u = used;
            while (u) {
                int bit = __ffsll(u) - 1;
                u &= u - 1;
                tpIdx[thr_i * NL_ + b * G_ + j++] = b * N_ + lane * 64 + bit;
            }
        }
    }
    __syncthreads();
    if (tid < 2) cnt[tid * B_ + b] = lcnt[tid];
}

// ---- S1: in-place per-(batch,bin) exclusive prefix over batches + totals --
__global__ __launch_bounds__(256) void s1_kernel(
    unsigned short* __restrict__ pbh,        // [B_][NBKT] -> becomes prefix
    unsigned* __restrict__ total)            // [NBKT]
{
    int bin = blockIdx.x * 256 + threadIdx.x;
    unsigned run = 0;
    for (int b = 0; b < B_; ++b) {           // coalesced across threads
        size_t o = (size_t)b * NBKT + bin;
        unsigned v = pbh[o];
        pbh[o] = (unsigned short)run;
        run += v;
    }
    total[bin] = run;
}

// ---- S2: exclusive scan of 1024 bin totals, single block ------------------
__global__ __launch_bounds__(1024) void s2_kernel(
    const unsigned* __restrict__ total, unsigned* __restrict__ binStart)
{
    __shared__ unsigned part[1024];
    int t = threadIdx.x;
    part[t] = total[t];
    __syncthreads();
    for (int off = 1; off < 1024; off <<= 1) {   // inclusive Hillis-Steele
        unsigned add = (t >= off) ? part[t - off] : 0u;
        unsigned v = part[t];
        __syncthreads();
        part[t] = v + add;
        __syncthreads();
    }
    binStart[t] = (t == 0) ? 0u : part[t - 1];
}

// ---- Scatter: deterministic positions, zero global atomics ----------------
__global__ __launch_bounds__(1024) void scatter_kernel(
    const float* __restrict__ conf,
    const unsigned short* __restrict__ pbh,  // now the exclusive prefix
    const unsigned* __restrict__ binStart,
    float2* __restrict__ sPair)
{
    __shared__ unsigned baseB[NBKT];   // 4 KiB
    __shared__ unsigned lofs[NBKT];    // 4 KiB
    const int tid = threadIdx.x;
    const int b = blockIdx.x;
    if (tid < NBKT) {
        baseB[tid] = binStart[tid] + pbh[(size_t)b * NBKT + tid];
        lofs[tid] = 0u;
    }
    __syncthreads();
    const float* cb = conf + (size_t)b * N_;
    #pragma unroll
    for (int s = 0; s < 4; ++s) {
        int n = s * 1024 + tid;
        if (n < N_) {
            float c = cb[n];
            unsigned bin = bucket_of(c);
            unsigned lo = atomicAdd(&lofs[bin], 1u);   // LDS atomic
            sPair[baseB[bin] + lo] = make_float2(c, __uint_as_float((unsigned)(b * N_ + n)));
        }
    }
}

// ---- Rank: one WAVE per TP slot; lanes stride the bucket ------------------
__global__ __launch_bounds__(256) void rank_kernel(
    const float* __restrict__ conf,
    const int* __restrict__ tpIdx,
    const int* __restrict__ cnt,
    const unsigned* __restrict__ total,
    const unsigned* __restrict__ binStart,
    const float2* __restrict__ sPair,
    int* __restrict__ tpRank)
{
    const int lane = threadIdx.x & 63;
    const int w = (blockIdx.x << 2) | (threadIdx.x >> 6);   // global wave id
    if (w >= 2 * NL_) return;
    const int thr_i = w / NL_;
    const int t = w - thr_i * NL_;
    const int batch = t / G_;
    const int j = t - batch * G_;

    if (j < cnt[thr_i * B_ + batch]) {
        int e = tpIdx[thr_i * NL_ + t];
        float c = conf[e];
        unsigned bin = bucket_of(c);
        unsigned lo = binStart[bin], n = total[bin];
        int r = M_ - (int)lo - (int)n;   // strictly-better buckets
        for (unsigned base = 0; base < n; base += 64) {
            unsigned k = base + lane;
            bool pred = false;
            if (k < n) {
                float2 p = sPair[lo + k];
                unsigned si = __float_as_uint(p.y);
                pred = (p.x > c) || (p.x == c && si < (unsigned)e);
            }
            r += (int)__popcll(__ballot(pred));   // wave-uniform partial sum
        }
        if (lane == 0) tpRank[thr_i * NL_ + t] = r;
    } else {
        if (lane == 0) tpRank[thr_i * NL_ + t] = M_ + t;   // distinct sentinel
    }
}

// ---- Pos1: partial counts, 4 t's per lane, K=16 u-tiles -------------------
__global__ __launch_bounds__(256) void pos1_kernel(
    const int* __restrict__ tpRank,
    int* __restrict__ pcount)          // [2][KP][NL_]
{
    __shared__ alignas(16) int tile[TILE];
    const int k = blockIdx.y, thr_i = blockIdx.z;
    const int* base = tpRank + thr_i * NL_;
    for (int i = threadIdx.x; i < TILE; i += 256)
        tile[i] = base[k * TILE + i];
    __syncthreads();

    const int t0 = blockIdx.x * 1024 + threadIdx.x;
    int r[4], c[4] = {0, 0, 0, 0};
    #pragma unroll
    for (int j = 0; j < 4; ++j) {
        int t = t0 + j * 256;
        r[j] = (t < NL_) ? base[t] : -1;   // ranks >= 0, so c stays 0
    }
    const int4* l4 = (const int4*)tile;
    #pragma unroll 4
    for (int i = 0; i < TILE / 4; ++i) {   // wave-uniform -> LDS broadcast
        int4 v = l4[i];
        #pragma unroll
        for (int j = 0; j < 4; ++j)
            c[j] += (v.x < r[j]) + (v.y < r[j]) + (v.z < r[j]) + (v.w < r[j]);
    }
    #pragma unroll
    for (int j = 0; j < 4; ++j) {
        int t = t0 + j * 256;
        if (t < NL_) pcount[(thr_i * KP + k) * NL_ + t] = c[j];
    }
}

// ---- Pos2: sum partials, scatter sorted ranks -----------------------------
__global__ __launch_bounds__(256) void pos2_kernel(
    const int* __restrict__ tpRank,
    const int* __restrict__ pcount,
    int* __restrict__ sortedRank)
{
    int gt = blockIdx.x * 256 + threadIdx.x;   // 0 .. 2*NL_-1
    int thr_i = gt / NL_;
    int t = gt - thr_i * NL_;
    int p = 0;
    #pragma unroll
    for (int k = 0; k < KP; ++k)
        p += pcount[(thr_i * KP + k) * NL_ + t];   // coalesced per k
    sortedRank[thr_i * NL_ + p] = tpRank[thr_i * NL_ + t];   // bijection
}

// ---- AP from sorted TP ranks. One block per threshold. --------------------
__global__ __launch_bounds__(1024) void ap_kernel(const int* __restrict__ sortedRank,
                                                  float* __restrict__ out)
{
    const int C = 13;   // 1024*13 = 13312 >= NL_
    int thr_i = blockIdx.x;
    int t = threadIdx.x;
    const int* sr = sortedRank + thr_i * NL_;

    float pr[C]; int rk[C];
    #pragma unroll
    for (int k = 0; k < C; ++k) {
        int i = t * C + k;
        rk[k] = (i < NL_) ? sr[i] : 0x7FFFFFFF;
        pr[k] = (rk[k] < M_) ? (float)(i + 1) / (float)(rk[k] + 1) : -1.0f;
    }
    float suf[C];
    float run = -1.0f;
    #pragma unroll
    for (int k = C - 1; k >= 0; --k) { run = fmaxf(run, pr[k]); suf[k] = run; }

    __shared__ float cmax[1024];
    cmax[t] = run;
    __syncthreads();
    for (int off = 1; off < 1024; off <<= 1) {   // inclusive suffix-max scan
        float v = cmax[t];
        float o = (t + off < 1024) ? cmax[t + off] : -1.0f;
        __syncthreads();
        cmax[t] = fmaxf(v, o);
        __syncthreads();
    }
    float follow = (t + 1 < 1024) ? cmax[t + 1] : -1.0f;

    double acc = 0.0;
    #pragma unroll
    for (int k = 0; k < C; ++k) {
        int i = t * C + k;
        if (rk[k] >= 1 && rk[k] < M_) {   // global rank 0 excluded by ref curve
            float smax = fmaxf(suf[k], follow);
            float rhi = (float)(i + 1) / 12800.0f;
            float rlo = (float)i / 12800.0f;
            acc += (double)((rhi - rlo) * smax);
        }
    }
    __shared__ double red[1024];
    red[t] = acc;
    __syncthreads();
    for (int off = 512; off >= 1; off >>= 1) {
        if (t < off) red[t] += red[t + off];
        __syncthreads();
    }
    if (t == 0) out[thr_i] = (float)red[0];
}

extern "C" void kernel_launch(void* const* d_in, const int* in_sizes, int n_in,
                              void* d_out, int out_size, void* d_ws, size_t ws_size,
                              hipStream_t stream) {
    const float* scores = (const float*)d_in[0];   // [B,N]
    const float* seg    = (const float*)d_in[1];   // [B,N,2]
    const float* gts    = (const float*)d_in[2];   // [B,G,2]
    float* out = (float*)d_out;

    char* p = (char*)d_ws;
    int*            cnt        = (int*)p;             p += 4096;                  // 2KB used
    int*            tpIdx      = (int*)p;             p += 2 * NL_ * 4;           // 100 KB
    int*            tpRank     = (int*)p;             p += 2 * NL_ * 4;           // 100 KB
    int*            sortedRank = (int*)p;             p += 2 * NL_ * 4;           // 100 KB
    unsigned*       total      = (unsigned*)p;        p += NBKT * 4;              // 4 KB
    unsigned*       binStart   = (unsigned*)p;        p += NBKT * 4;              // 4 KB
    unsigned short* pbh        = (unsigned short*)p;  p += (size_t)B_ * NBKT * 2; // 512 KB
    float2*         sPair      = (float2*)p;          p += (size_t)M_ * 8;        // 8 MB
    int*            pcount     = (int*)sPair;   // aliases sPair (dead after rank)
    (void)ws_size; (void)in_sizes; (void)n_in; (void)out_size;     // total ~9.04 MB

    // No memset: every workspace word read downstream is written upstream.
    tp_kernel<<<B_, 1024, 0, stream>>>(seg, gts, scores, tpIdx, cnt, pbh);
    s1_kernel<<<NBKT / 256, 256, 0, stream>>>(pbh, total);
    s2_kernel<<<1, 1024, 0, stream>>>(total, binStart);
    scatter_kernel<<<B_, 1024, 0, stream>>>(scores, pbh, binStart, sPair);
    rank_kernel<<<(2 * NL_ + 3) / 4, 256, 0, stream>>>(scores, tpIdx, cnt,
                                                       total, binStart, sPair, tpRank);
    pos1_kernel<<<dim3(13, KP, 2), 256, 0, stream>>>(tpRank, pcount);
    pos2_kernel<<<2 * NL_ / 256, 256, 0, stream>>>(tpRank, pcount, sortedRank);
    ap_kernel<<<2, 1024, 0, stream>>>(sortedRank, out);
}